// Round 3
// baseline (503.340 us; speedup 1.0000x reference)
//
#include <hip/hip_runtime.h>
#include <hip/hip_bf16.h>

#define DI static __device__ __forceinline__

typedef unsigned short u16;
typedef unsigned int   u32;
typedef __bf16 bf16_t;
typedef __bf16 bf16x8 __attribute__((ext_vector_type(8)));
typedef float  f32x4  __attribute__((ext_vector_type(4)));

union BF8 { ushort4 u4[2]; bf16x8 v; };

DI u16 f2bf(float f) { union { bf16_t b; u16 u; } c; c.b = (bf16_t)f; return c.u; }
DI float bf2f(u32 lo) { union { u32 u; float f; } c; c.u = lo << 16; return c.f; }
DI float fast_tanh(float x) { float e = __expf(2.0f * x); return 1.0f - 2.0f / (e + 1.0f); }

// ---------------- problem constants ----------------
constexpr int NB   = 64;    // batch
constexpr int CIMG = 256;
constexpr int HID  = 512;
constexpr int HW   = 4096;
constexpr int TT   = 128;
constexpr int NTOT = HW + TT; // 4224

// ---------------- ws layout (bytes) ----------------
constexpr size_t WS_WIMG  = 0;                                  // 128*256 bf16
constexpr size_t WS_WTXT  = WS_WIMG  + 128ull*256*2;            // 128*512 bf16
constexpr size_t WS_WIPC  = WS_WTXT  + 128ull*512*2;            // 128*128 bf16
constexpr size_t WS_WQPC  = WS_WIPC  + 128ull*128*2;            // 128*128 bf16
constexpr size_t WS_IFEAT = WS_WQPC  + 128ull*128*2;            // 64*128*4096 bf16
constexpr size_t WS_QFEAT = WS_IFEAT + (size_t)NB*128*HW*2;     // 64*128*128 bf16
constexpr size_t WS_QFP   = WS_QFEAT + (size_t)NB*128*TT*2;     // 64*128*128 f32
constexpr size_t WS_LOGIT = WS_QFP   + (size_t)NB*128*TT*4;     // 64*4224 f32
constexpr size_t WS_ISUM  = WS_LOGIT + (size_t)NB*NTOT*4;       // 64*128 f32
constexpr size_t WS_QSUM  = WS_ISUM  + (size_t)NB*128*4;        // 64*128 f32
constexpr size_t WS_QATT  = WS_QSUM  + (size_t)NB*128*4;        // 64*128 f32

// ---------------- tiny helper kernels ----------------
__global__ void k_zero(float* __restrict__ p, int n) {
    int i = blockIdx.x * 256 + threadIdx.x;
    if (i < n) p[i] = 0.0f;
}

__global__ void k_convert(const float* __restrict__ s, bf16_t* __restrict__ d, int n) {
    int i = blockIdx.x * 256 + threadIdx.x;
    if (i < n) d[i] = (bf16_t)s[i];
}

// qfeatatt[b,a] = (sum_t in_qfeat / T) dot W_qfc[a,:]
__global__ void k_qatt(const float* __restrict__ qsum, const float* __restrict__ Wqfc,
                       float* __restrict__ qatt) {
    int b = blockIdx.x, a = threadIdx.x;  // 128 threads
    const float* qs = qsum + b * 128;
    const float* wr = Wqfc + a * 128;
    float s = 0.f;
    for (int m = 0; m < 128; ++m) s += qs[m] * wr[m];
    qatt[b * 128 + a] = s * (1.0f / 128.0f);
}

// text-branch logits: logits[b, 4096+t] = sum_a W_att[a]*tanh(ifeatatt[b,a]+qfp[b,a,t])
__global__ void k_textlogits(const float* __restrict__ isum, const float* __restrict__ Wifc,
                             const float* __restrict__ Watt, const float* __restrict__ qfp,
                             float* __restrict__ logits) {
    int b = blockIdx.x, tid = threadIdx.x;  // 256 threads
    __shared__ float ia[128];
    __shared__ float wat[128];
    __shared__ float part[2][128];
    if (tid < 128) {
        float s = 0.f;
        const float* is = isum + b * 128;
        const float* wr = Wifc + tid * 128;
        for (int m = 0; m < 128; ++m) s += is[m] * wr[m];
        ia[tid]  = s * (1.0f / 4096.0f);
        wat[tid] = Watt[tid];
    }
    __syncthreads();
    int t = tid & 127, h = tid >> 7;
    const float* qp = qfp + ((size_t)b * 128 + h * 64) * 128 + t;
    float s = 0.f;
    for (int a0 = 0; a0 < 64; ++a0) {
        int a = h * 64 + a0;
        s += wat[a] * fast_tanh(ia[a] + qp[(size_t)a0 * 128]);
    }
    part[h][t] = s;
    __syncthreads();
    if (tid < 128) logits[b * NTOT + 4096 + tid] = part[0][tid] + part[1][tid];
}

// per-batch softmax over 4224 logits -> att (f32, into d_out region)
__global__ void k_softmax(const float* __restrict__ logits, float* __restrict__ att) {
    int b = blockIdx.x, tid = threadIdx.x;  // 256 threads
    const float* L = logits + (size_t)b * NTOT;
    float* O = att + (size_t)b * NTOT;
    __shared__ float red[4];
    __shared__ float red2[4];
    float mx = -3.0e38f;
    for (int i = tid; i < NTOT; i += 256) mx = fmaxf(mx, L[i]);
    for (int off = 1; off < 64; off <<= 1) mx = fmaxf(mx, __shfl_xor(mx, off, 64));
    if ((tid & 63) == 0) red[tid >> 6] = mx;
    __syncthreads();
    mx = fmaxf(fmaxf(red[0], red[1]), fmaxf(red[2], red[3]));
    float s = 0.f;
    for (int i = tid; i < NTOT; i += 256) {
        float e = __expf(L[i] - mx);
        O[i] = e;
        s += e;
    }
    for (int off = 1; off < 64; off <<= 1) s += __shfl_xor(s, off, 64);
    if ((tid & 63) == 0) red2[tid >> 6] = s;
    __syncthreads();
    float inv = 1.0f / (red2[0] + red2[1] + red2[2] + red2[3]);
    for (int i = tid; i < NTOT; i += 256) O[i] *= inv;
}

// att_feat[b,m] = sum_n ifeat[b,m,n]*att[b,n] + sum_t qfeat[b,m,t]*att[b,4096+t]
__global__ void k_attfeat(const bf16_t* __restrict__ ifeat, const bf16_t* __restrict__ qfeat,
                          const float* __restrict__ att, float* __restrict__ out) {
    int mg = blockIdx.x;  // 16 groups of 8 rows
    int b  = blockIdx.y;
    int tid = threadIdx.x;  // 256
    const u16* F = (const u16*)ifeat + ((size_t)b * 128 + mg * 8) * HW;
    const u16* Q = (const u16*)qfeat + ((size_t)b * 128 + mg * 8) * TT;
    const float* A_ = att + (size_t)b * NTOT;
    float acc[8] = {0, 0, 0, 0, 0, 0, 0, 0};
    for (int i = tid; i < HW / 2; i += 256) {
        float2 a2 = *(const float2*)&A_[2 * i];
#pragma unroll
        for (int r = 0; r < 8; ++r) {
            u32 pk = *(const u32*)&F[(size_t)r * HW + 2 * i];
            acc[r] += bf2f(pk & 0xffffu) * a2.x + bf2f(pk >> 16) * a2.y;
        }
    }
    for (int i = tid; i < TT / 2; i += 256) {  // only tid < 64 active
        float2 a2 = *(const float2*)&A_[HW + 2 * i];
#pragma unroll
        for (int r = 0; r < 8; ++r) {
            u32 pk = *(const u32*)&Q[(size_t)r * TT + 2 * i];
            acc[r] += bf2f(pk & 0xffffu) * a2.x + bf2f(pk >> 16) * a2.y;
        }
    }
    __shared__ float red[4][8];
    int lane = tid & 63, wv = tid >> 6;
#pragma unroll
    for (int r = 0; r < 8; ++r) {
        float s = acc[r];
        s += __shfl_xor(s, 1, 64);
        s += __shfl_xor(s, 2, 64);
        s += __shfl_xor(s, 4, 64);
        s += __shfl_xor(s, 8, 64);
        s += __shfl_xor(s, 16, 64);
        s += __shfl_xor(s, 32, 64);
        if (lane == 0) red[wv][r] = s;
    }
    __syncthreads();
    if (tid < 8)
        out[(size_t)b * 128 + mg * 8 + tid] = red[0][tid] + red[1][tid] + red[2][tid] + red[3][tid];
}

// ---------------- the fused chain kernel ----------------
// Computes, for a 64-column tile of batch b:
//   Y1 = tanh(Wa @ X)            (GEMM1, MFMA bf16)   -> feat_out (bf16), row-sums (atomics)
//   P  = Wp @ Y1                 (GEMM2, MFMA bf16)
//   IMG:  logits[n] = sum_a Watt[a]*tanh(qatt[a]+P[a,n])
//   !IMG: proj_out[b,a,t] = P[a,t]
template <int C, bool IMG>
__global__ __launch_bounds__(256) void k_chain(
    const float* __restrict__ xin, const bf16_t* __restrict__ Wa, const bf16_t* __restrict__ Wp,
    const float* __restrict__ qatt, const float* __restrict__ Watt, bf16_t* __restrict__ feat_out,
    float* __restrict__ sums, float* __restrict__ proj_out, int S) {
    constexpr int LDX = C + 4;  // (LDX/2)%32 == 2 -> bank = 2*col + k/2 (balanced)
    __shared__ u16 Xl[64 * LDX];       // X tile, transposed: Xl[col][c], bf16
    __shared__ u16 Y1[64 * 132];       // Y1[col][m]  (m-major per col, for GEMM2 B-frags)
    __shared__ u16 Y1N[128 * 68];      // Y1N[m][col] (n-major per row, for global write)
    __shared__ float lred[4][64];
    __shared__ float qf_l[128];
    __shared__ float wa_l[128];

    const int tid = threadIdx.x;
    const int b  = blockIdx.y;
    const int n0 = blockIdx.x * 64;
    const int l  = tid & 63, w = tid >> 6;
    const int lr = l & 15, g = l >> 4;

    if constexpr (IMG) {
        if (tid < 128) {
            qf_l[tid] = qatt[b * 128 + tid];
            wa_l[tid] = Watt[tid];
        }
    }

    // ---- stage X tile transposed as bf16 ----
    {
        const int col = tid & 63, cg = tid >> 6;
        constexpr int CQ = C / 4;
        const float* xb = xin + (size_t)b * C * S + n0 + col;
#pragma unroll 4
        for (int i = 0; i < CQ; i += 4) {
            int c = cg * CQ + i;
            float f0 = xb[(size_t)(c + 0) * S];
            float f1 = xb[(size_t)(c + 1) * S];
            float f2 = xb[(size_t)(c + 2) * S];
            float f3 = xb[(size_t)(c + 3) * S];
            ushort4 p4;
            p4.x = f2bf(f0); p4.y = f2bf(f1); p4.z = f2bf(f2); p4.w = f2bf(f3);
            *(ushort4*)&Xl[col * LDX + c] = p4;
        }
    }
    __syncthreads();

    // ---- GEMM1: acc1[rt][ct] = Wa(rows w*32+rt*16..) @ X(cols ct*16..) ----
    f32x4 acc1[2][4];
#pragma unroll
    for (int rt = 0; rt < 2; ++rt)
#pragma unroll
        for (int ct = 0; ct < 4; ++ct)
#pragma unroll
            for (int r = 0; r < 4; ++r) acc1[rt][ct][r] = 0.f;

    const bf16_t* wa0 = Wa + (size_t)(w * 32 + lr) * C + g * 8;
#pragma unroll
    for (int ks = 0; ks < C / 32; ++ks) {
        bf16x8 af0 = *(const bf16x8*)(wa0 + ks * 32);
        bf16x8 af1 = *(const bf16x8*)(wa0 + (size_t)16 * C + ks * 32);
#pragma unroll
        for (int ct = 0; ct < 4; ++ct) {
            BF8 bu;
            const u16* p = &Xl[(ct * 16 + lr) * LDX + ks * 32 + g * 8];
            bu.u4[0] = *(const ushort4*)p;
            bu.u4[1] = *(const ushort4*)(p + 4);
            acc1[0][ct] = __builtin_amdgcn_mfma_f32_16x16x32_bf16(af0, bu.v, acc1[0][ct], 0, 0, 0);
            acc1[1][ct] = __builtin_amdgcn_mfma_f32_16x16x32_bf16(af1, bu.v, acc1[1][ct], 0, 0, 0);
        }
    }

    // ---- tanh; row sums (for mean); scatter Y1 / Y1N ----
    float y[2][4][4];
#pragma unroll
    for (int rt = 0; rt < 2; ++rt)
#pragma unroll
        for (int ct = 0; ct < 4; ++ct)
#pragma unroll
            for (int r = 0; r < 4; ++r) y[rt][ct][r] = fast_tanh(acc1[rt][ct][r]);

#pragma unroll
    for (int rt = 0; rt < 2; ++rt)
#pragma unroll
        for (int r = 0; r < 4; ++r) {
            float s = y[rt][0][r] + y[rt][1][r] + y[rt][2][r] + y[rt][3][r];
            s += __shfl_xor(s, 1, 64);
            s += __shfl_xor(s, 2, 64);
            s += __shfl_xor(s, 4, 64);
            s += __shfl_xor(s, 8, 64);
            if (lr == 0) atomicAdd(&sums[b * 128 + w * 32 + rt * 16 + g * 4 + r], s);
        }

#pragma unroll
    for (int rt = 0; rt < 2; ++rt)
#pragma unroll
        for (int ct = 0; ct < 4; ++ct) {
            int m0 = w * 32 + rt * 16 + g * 4;
            int c2 = ct * 16 + lr;
#pragma unroll
            for (int r = 0; r < 4; r += 2) {
                u32 pk = (u32)f2bf(y[rt][ct][r]) | ((u32)f2bf(y[rt][ct][r + 1]) << 16);
                *(u32*)&Y1[c2 * 132 + m0 + r] = pk;
            }
#pragma unroll
            for (int r = 0; r < 4; ++r) Y1N[(m0 + r) * 68 + c2] = f2bf(y[rt][ct][r]);
        }
    __syncthreads();

    // ---- GEMM2: acc2 = Wp @ Y1 ----
    f32x4 acc2[2][4];
#pragma unroll
    for (int rt = 0; rt < 2; ++rt)
#pragma unroll
        for (int ct = 0; ct < 4; ++ct)
#pragma unroll
            for (int r = 0; r < 4; ++r) acc2[rt][ct][r] = 0.f;

    const bf16_t* wp0 = Wp + (size_t)(w * 32 + lr) * 128 + g * 8;
#pragma unroll
    for (int ks = 0; ks < 4; ++ks) {
        bf16x8 af0 = *(const bf16x8*)(wp0 + ks * 32);
        bf16x8 af1 = *(const bf16x8*)(wp0 + 16 * 128 + ks * 32);
#pragma unroll
        for (int ct = 0; ct < 4; ++ct) {
            BF8 bu;
            const u16* p = &Y1[(ct * 16 + lr) * 132 + ks * 32 + g * 8];
            bu.u4[0] = *(const ushort4*)p;
            bu.u4[1] = *(const ushort4*)(p + 4);
            acc2[0][ct] = __builtin_amdgcn_mfma_f32_16x16x32_bf16(af0, bu.v, acc2[0][ct], 0, 0, 0);
            acc2[1][ct] = __builtin_amdgcn_mfma_f32_16x16x32_bf16(af1, bu.v, acc2[1][ct], 0, 0, 0);
        }
    }

    // ---- write tanh-feature tile to global (bf16, n-contiguous) ----
    {
        u16* fb = (u16*)feat_out + (size_t)b * 128 * S + n0;
#pragma unroll
        for (int it = 0; it < 8; ++it) {
            int m = w * 32 + it * 4 + g;
            int nc = lr * 4;
            ushort4 v = *(const ushort4*)&Y1N[m * 68 + nc];
            *(ushort4*)(fb + (size_t)m * S + nc) = v;
        }
    }

    if constexpr (IMG) {
        // logits[n] = sum_a Watt[a]*tanh(qatt[a] + P[a,n])
        float ps[4] = {0, 0, 0, 0};
#pragma unroll
        for (int rt = 0; rt < 2; ++rt)
#pragma unroll
            for (int r = 0; r < 4; ++r) {
                int a = w * 32 + rt * 16 + g * 4 + r;
                float qa = qf_l[a], wv = wa_l[a];
#pragma unroll
                for (int ct = 0; ct < 4; ++ct) ps[ct] += wv * fast_tanh(qa + acc2[rt][ct][r]);
            }
#pragma unroll
        for (int ct = 0; ct < 4; ++ct) {
            ps[ct] += __shfl_xor(ps[ct], 16, 64);
            ps[ct] += __shfl_xor(ps[ct], 32, 64);
        }
        if (g == 0) {
#pragma unroll
            for (int ct = 0; ct < 4; ++ct) lred[w][ct * 16 + lr] = ps[ct];
        }
        __syncthreads();
        if (tid < 64)
            proj_out[(size_t)b * NTOT + n0 + tid] =
                lred[0][tid] + lred[1][tid] + lred[2][tid] + lred[3][tid];
    } else {
        // store raw projection P[a,t] (f32)
#pragma unroll
        for (int rt = 0; rt < 2; ++rt)
#pragma unroll
            for (int ct = 0; ct < 4; ++ct) {
                int a = w * 32 + rt * 16 + g * 4;
                int t = n0 + ct * 16 + lr;
#pragma unroll
                for (int r = 0; r < 4; ++r)
                    proj_out[((size_t)b * 128 + a + r) * 128 + t] = acc2[rt][ct][r];
            }
    }
}

// ---------------- launch ----------------
extern "C" void kernel_launch(void* const* d_in, const int* in_sizes, int n_in, void* d_out,
                              int out_size, void* d_ws, size_t ws_size, hipStream_t stream) {
    (void)in_sizes; (void)n_in; (void)out_size; (void)ws_size;
    const float* img  = (const float*)d_in[0];
    const float* txt  = (const float*)d_in[1];
    const float* Wimg = (const float*)d_in[2];
    const float* Wtxt = (const float*)d_in[3];
    const float* Wqfc = (const float*)d_in[4];
    const float* Wifc = (const float*)d_in[5];
    const float* Wipc = (const float*)d_in[6];
    const float* Wqpc = (const float*)d_in[7];
    const float* Watt = (const float*)d_in[8];

    char* ws = (char*)d_ws;
    bf16_t* wimg_b  = (bf16_t*)(ws + WS_WIMG);
    bf16_t* wtxt_b  = (bf16_t*)(ws + WS_WTXT);
    bf16_t* wipc_b  = (bf16_t*)(ws + WS_WIPC);
    bf16_t* wqpc_b  = (bf16_t*)(ws + WS_WQPC);
    bf16_t* ifeat_b = (bf16_t*)(ws + WS_IFEAT);
    bf16_t* qfeat_b = (bf16_t*)(ws + WS_QFEAT);
    float*  qfp     = (float*)(ws + WS_QFP);
    float*  logits  = (float*)(ws + WS_LOGIT);
    float*  isum    = (float*)(ws + WS_ISUM);
    float*  qsum    = (float*)(ws + WS_QSUM);
    float*  qatt    = (float*)(ws + WS_QATT);

    float* out_feat = (float*)d_out;             // [64,128]
    float* out_att  = (float*)d_out + 64 * 128;  // [64,4224]

    // zero the atomic accumulators (ws is poisoned 0xAA before every call)
    k_zero<<<(2 * 64 * 128 + 255) / 256, 256, 0, stream>>>(isum, 2 * 64 * 128);

    int n1 = 128 * 256, n2 = 128 * 512, n3 = 128 * 128;
    k_convert<<<(n1 + 255) / 256, 256, 0, stream>>>(Wimg, wimg_b, n1);
    k_convert<<<(n2 + 255) / 256, 256, 0, stream>>>(Wtxt, wtxt_b, n2);
    k_convert<<<(n3 + 255) / 256, 256, 0, stream>>>(Wipc, wipc_b, n3);
    k_convert<<<(n3 + 255) / 256, 256, 0, stream>>>(Wqpc, wqpc_b, n3);

    // text chain: in_qfeat (bf16), qsum, qfeatproj (f32)
    k_chain<512, false><<<dim3(2, 64), 256, 0, stream>>>(txt, wtxt_b, wqpc_b, nullptr, nullptr,
                                                         qfeat_b, qsum, qfp, TT);
    // qfeatatt
    k_qatt<<<64, 128, 0, stream>>>(qsum, Wqfc, qatt);
    // image chain: in_ifeat (bf16), isum, image logits
    k_chain<256, true><<<dim3(64, 64), 256, 0, stream>>>(img, wimg_b, wipc_b, qatt, Watt,
                                                         ifeat_b, isum, logits, HW);
    // text-branch logits
    k_textlogits<<<64, 256, 0, stream>>>(isum, Wifc, Watt, qfp, logits);
    // softmax -> att (directly into d_out att region)
    k_softmax<<<64, 256, 0, stream>>>(logits, out_att);
    // att_feat
    k_attfeat<<<dim3(16, 64), 256, 0, stream>>>(ifeat_b, qfeat_b, out_att, out_feat);
}

// Round 4
// 491.847 us; speedup vs baseline: 1.0234x; 1.0234x over previous
//
#include <hip/hip_runtime.h>
#include <hip/hip_bf16.h>

#define DI static __device__ __forceinline__

typedef unsigned short u16;
typedef unsigned int   u32;
typedef __bf16 bf16_t;
typedef __bf16 bf16x8 __attribute__((ext_vector_type(8)));
typedef float  f32x4  __attribute__((ext_vector_type(4)));

union BF8 { ushort4 u4[2]; bf16x8 v; };

DI u16 f2bf(float f) { union { bf16_t b; u16 u; } c; c.b = (bf16_t)f; return c.u; }
DI float bf2f(u32 lo) { union { u32 u; float f; } c; c.u = lo << 16; return c.f; }
DI float fast_tanh(float x) { float e = __expf(2.0f * x); return 1.0f - 2.0f / (e + 1.0f); }

// ---------------- problem constants ----------------
constexpr int NB   = 64;    // batch
constexpr int HW   = 4096;
constexpr int TT   = 128;
constexpr int NTOT = HW + TT; // 4224

// ---------------- ws layout (bytes) ----------------
constexpr size_t WS_WIMG  = 0;                                  // 128*256 bf16
constexpr size_t WS_WTXT  = WS_WIMG  + 128ull*256*2;            // 128*512 bf16
constexpr size_t WS_WIPC  = WS_WTXT  + 128ull*512*2;            // 128*128 bf16
constexpr size_t WS_WQPC  = WS_WIPC  + 128ull*128*2;            // 128*128 bf16
constexpr size_t WS_IFEAT = WS_WQPC  + 128ull*128*2;            // 64*128*4096 bf16
constexpr size_t WS_QFEAT = WS_IFEAT + (size_t)NB*128*HW*2;     // 64*128*128 bf16
constexpr size_t WS_QFP   = WS_QFEAT + (size_t)NB*128*TT*2;     // 64*128*128 f32
constexpr size_t WS_LOGIT = WS_QFP   + (size_t)NB*128*TT*4;     // 64*4224 f32
constexpr size_t WS_ISUM  = WS_LOGIT + (size_t)NB*NTOT*4;       // 64*128 f32
constexpr size_t WS_QSUM  = WS_ISUM  + (size_t)NB*128*4;        // 64*128 f32
constexpr size_t WS_QATT  = WS_QSUM  + (size_t)NB*128*4;        // 64*128 f32

// ---------------- tiny helper kernels ----------------
__global__ void k_zero(float* __restrict__ p, int n) {
    int i = blockIdx.x * 256 + threadIdx.x;
    if (i < n) p[i] = 0.0f;
}

// all four weight tensors converted in one launch
__global__ void k_convert4(const float* __restrict__ s0, const float* __restrict__ s1,
                           const float* __restrict__ s2, const float* __restrict__ s3,
                           bf16_t* __restrict__ d0, bf16_t* __restrict__ d1,
                           bf16_t* __restrict__ d2, bf16_t* __restrict__ d3) {
    int i = blockIdx.x * 256 + threadIdx.x;  // total 131072
    if (i < 32768) { d0[i] = (bf16_t)s0[i]; return; }
    i -= 32768;
    if (i < 65536) { d1[i] = (bf16_t)s1[i]; return; }
    i -= 65536;
    if (i < 16384) { d2[i] = (bf16_t)s2[i]; return; }
    i -= 16384;
    d3[i] = (bf16_t)s3[i];
}

// qfeatatt[b,a] = (sum_t in_qfeat / T) dot W_qfc[a,:]
__global__ void k_qatt(const float* __restrict__ qsum, const float* __restrict__ Wqfc,
                       float* __restrict__ qatt) {
    int b = blockIdx.x, a = threadIdx.x;  // 128 threads
    const float* qs = qsum + b * 128;
    const float* wr = Wqfc + a * 128;
    float s = 0.f;
    for (int m = 0; m < 128; ++m) s += qs[m] * wr[m];
    qatt[b * 128 + a] = s * (1.0f / 128.0f);
}

// text-branch logits: logits[b, 4096+t] = sum_a W_att[a]*tanh(ifeatatt[b,a]+qfp[b,a,t])
__global__ void k_textlogits(const float* __restrict__ isum, const float* __restrict__ Wifc,
                             const float* __restrict__ Watt, const float* __restrict__ qfp,
                             float* __restrict__ logits) {
    int b = blockIdx.x, tid = threadIdx.x;  // 256 threads
    __shared__ float ia[128];
    __shared__ float wat[128];
    __shared__ float part[2][128];
    if (tid < 128) {
        float s = 0.f;
        const float* is = isum + b * 128;
        const float* wr = Wifc + tid * 128;
        for (int m = 0; m < 128; ++m) s += is[m] * wr[m];
        ia[tid]  = s * (1.0f / 4096.0f);
        wat[tid] = Watt[tid];
    }
    __syncthreads();
    int t = tid & 127, h = tid >> 7;
    const float* qp = qfp + ((size_t)b * 128 + h * 64) * 128 + t;
    float s = 0.f;
    for (int a0 = 0; a0 < 64; ++a0) {
        int a = h * 64 + a0;
        s += wat[a] * fast_tanh(ia[a] + qp[(size_t)a0 * 128]);
    }
    part[h][t] = s;
    __syncthreads();
    if (tid < 128) logits[b * NTOT + 4096 + tid] = part[0][tid] + part[1][tid];
}

// per-batch softmax over 4224 logits -> att (f32, into d_out region)
__global__ void k_softmax(const float* __restrict__ logits, float* __restrict__ att) {
    int b = blockIdx.x, tid = threadIdx.x;  // 256 threads
    const float* L = logits + (size_t)b * NTOT;
    float* O = att + (size_t)b * NTOT;
    __shared__ float red[4];
    __shared__ float red2[4];
    float mx = -3.0e38f;
    for (int i = tid; i < NTOT; i += 256) mx = fmaxf(mx, L[i]);
    for (int off = 1; off < 64; off <<= 1) mx = fmaxf(mx, __shfl_xor(mx, off, 64));
    if ((tid & 63) == 0) red[tid >> 6] = mx;
    __syncthreads();
    mx = fmaxf(fmaxf(red[0], red[1]), fmaxf(red[2], red[3]));
    float s = 0.f;
    for (int i = tid; i < NTOT; i += 256) {
        float e = __expf(L[i] - mx);
        O[i] = e;
        s += e;
    }
    for (int off = 1; off < 64; off <<= 1) s += __shfl_xor(s, off, 64);
    if ((tid & 63) == 0) red2[tid >> 6] = s;
    __syncthreads();
    float inv = 1.0f / (red2[0] + red2[1] + red2[2] + red2[3]);
    for (int i = tid; i < NTOT; i += 256) O[i] *= inv;
}

// att_feat[b,m] += partial over n-range; 4-way n-split, atomic accumulate
__global__ void k_attfeat(const bf16_t* __restrict__ ifeat, const bf16_t* __restrict__ qfeat,
                          const float* __restrict__ att, float* __restrict__ out) {
    int mg = blockIdx.x;   // 16 groups of 8 rows
    int ns = blockIdx.y;   // 4 n-splits
    int b  = blockIdx.z;   // 64
    int tid = threadIdx.x; // 256
    const u16* F = (const u16*)ifeat + ((size_t)b * 128 + mg * 8) * HW;
    const u16* Q = (const u16*)qfeat + ((size_t)b * 128 + mg * 8) * TT;
    const float* A_ = att + (size_t)b * NTOT;
    float acc[8] = {0, 0, 0, 0, 0, 0, 0, 0};
    int i0 = ns * 512;  // u32 units; HW/2 = 2048 total
#pragma unroll
    for (int it = 0; it < 2; ++it) {
        int i = i0 + it * 256 + tid;
        float2 a2 = *(const float2*)&A_[2 * i];
#pragma unroll
        for (int r = 0; r < 8; ++r) {
            u32 pk = *(const u32*)&F[(size_t)r * HW + 2 * i];
            acc[r] += bf2f(pk & 0xffffu) * a2.x + bf2f(pk >> 16) * a2.y;
        }
    }
    if (ns == 0 && tid < TT / 2) {
        float2 a2 = *(const float2*)&A_[HW + 2 * tid];
#pragma unroll
        for (int r = 0; r < 8; ++r) {
            u32 pk = *(const u32*)&Q[(size_t)r * TT + 2 * tid];
            acc[r] += bf2f(pk & 0xffffu) * a2.x + bf2f(pk >> 16) * a2.y;
        }
    }
    __shared__ float red[4][8];
    int lane = tid & 63, wv = tid >> 6;
#pragma unroll
    for (int r = 0; r < 8; ++r) {
        float s = acc[r];
        s += __shfl_xor(s, 1, 64);
        s += __shfl_xor(s, 2, 64);
        s += __shfl_xor(s, 4, 64);
        s += __shfl_xor(s, 8, 64);
        s += __shfl_xor(s, 16, 64);
        s += __shfl_xor(s, 32, 64);
        if (lane == 0) red[wv][r] = s;
    }
    __syncthreads();
    if (tid < 8)
        atomicAdd(&out[(size_t)b * 128 + mg * 8 + tid],
                  red[0][tid] + red[1][tid] + red[2][tid] + red[3][tid]);
}

// ---------------- the fused chain kernel ----------------
// Per 64-column tile of batch b:
//   Y1 = tanh(Wa @ X)   (GEMM1, chunked-K staging)  -> feat_out (bf16), row-sums (atomics)
//   P  = Wp @ Y1        (GEMM2)
//   IMG:  logits[n] = sum_a Watt[a]*tanh(qatt[a]+P[a,n]);  !IMG: proj_out = P (f32)
// LDS budget ~36 KB -> 4 blocks/CU.
template <int C, bool IMG>
__global__ __launch_bounds__(256, 4) void k_chain(
    const float* __restrict__ xin, const bf16_t* __restrict__ Wa, const bf16_t* __restrict__ Wp,
    const float* __restrict__ qatt, const float* __restrict__ Watt, bf16_t* __restrict__ feat_out,
    float* __restrict__ sums, float* __restrict__ proj_out, int S) {
    constexpr int NCH = C / 128;       // K-chunks of 128
    __shared__ u16 XY[128 * 68];       // phase 1: X chunk transposed [col][c2], LD=132 (8448 used)
                                       // phase 2: Y1N [m][col], LD=68 (8704 used)
    __shared__ u16 Y1[64 * 132];       // Y1[col][m] m-major per col (GEMM2 B-frags)
    __shared__ float lred[4][64];
    __shared__ float qf_l[128];
    __shared__ float wa_l[128];

    const int tid = threadIdx.x;
    const int b  = blockIdx.y;
    const int n0 = blockIdx.x * 64;
    const int l  = tid & 63, w = tid >> 6;
    const int lr = l & 15, g = l >> 4;

    if constexpr (IMG) {
        if (tid < 128) {
            qf_l[tid] = qatt[b * 128 + tid];
            wa_l[tid] = Watt[tid];
        }
    }

    f32x4 acc1[2][4];
#pragma unroll
    for (int rt = 0; rt < 2; ++rt)
#pragma unroll
        for (int ct = 0; ct < 4; ++ct)
#pragma unroll
            for (int r = 0; r < 4; ++r) acc1[rt][ct][r] = 0.f;

    const bf16_t* wa0 = Wa + (size_t)(w * 32 + lr) * C + g * 8;
    const int colb = (tid & 15) * 4;  // staging: 4 cols per lane
    const int r0   = tid >> 4;        // staging: row within 16-row pass

    for (int h = 0; h < NCH; ++h) {
        // ---- stage chunk h: rows c = h*128 + c2, float4 along n, bf16 transpose-scatter ----
        {
            const float* xb = xin + (size_t)b * C * S + (size_t)h * 128 * S + n0 + colb;
#pragma unroll
            for (int p = 0; p < 8; ++p) {
                int c2 = p * 16 + r0;
                float4 f = *(const float4*)(xb + (size_t)c2 * S);
                u16 v[4] = {f2bf(f.x), f2bf(f.y), f2bf(f.z), f2bf(f.w)};
                int rot = c2 & 3;
#pragma unroll
                for (int s = 0; s < 4; ++s) {
                    int jj = (s + rot) & 3;
                    XY[(colb + jj) * 132 + c2] = v[jj];
                }
            }
        }
        __syncthreads();
        // ---- GEMM1 over this chunk ----
#pragma unroll
        for (int ks2 = 0; ks2 < 4; ++ks2) {
            int ks = h * 4 + ks2;
            bf16x8 af0 = *(const bf16x8*)(wa0 + ks * 32);
            bf16x8 af1 = *(const bf16x8*)(wa0 + (size_t)16 * C + ks * 32);
#pragma unroll
            for (int ct = 0; ct < 4; ++ct) {
                BF8 bu;
                const u16* p = &XY[(ct * 16 + lr) * 132 + ks2 * 32 + g * 8];
                bu.u4[0] = *(const ushort4*)p;
                bu.u4[1] = *(const ushort4*)(p + 4);
                acc1[0][ct] = __builtin_amdgcn_mfma_f32_16x16x32_bf16(af0, bu.v, acc1[0][ct], 0, 0, 0);
                acc1[1][ct] = __builtin_amdgcn_mfma_f32_16x16x32_bf16(af1, bu.v, acc1[1][ct], 0, 0, 0);
            }
        }
        __syncthreads();  // chunk consumed; XY free for next chunk (or Y1N)
    }

    // ---- tanh; row sums (for mean) ----
    float y[2][4][4];
#pragma unroll
    for (int rt = 0; rt < 2; ++rt)
#pragma unroll
        for (int ct = 0; ct < 4; ++ct)
#pragma unroll
            for (int r = 0; r < 4; ++r) y[rt][ct][r] = fast_tanh(acc1[rt][ct][r]);

#pragma unroll
    for (int rt = 0; rt < 2; ++rt)
#pragma unroll
        for (int r = 0; r < 4; ++r) {
            float s = y[rt][0][r] + y[rt][1][r] + y[rt][2][r] + y[rt][3][r];
            s += __shfl_xor(s, 1, 64);
            s += __shfl_xor(s, 2, 64);
            s += __shfl_xor(s, 4, 64);
            s += __shfl_xor(s, 8, 64);
            if (lr == 0) atomicAdd(&sums[b * 128 + w * 32 + rt * 16 + g * 4 + r], s);
        }

    // ---- scatter Y1 (m-major) + Y1N (n-major, aliases XY) ----
#pragma unroll
    for (int rt = 0; rt < 2; ++rt)
#pragma unroll
        for (int ct = 0; ct < 4; ++ct) {
            int m0 = w * 32 + rt * 16 + g * 4;
            int c2 = ct * 16 + lr;
#pragma unroll
            for (int r = 0; r < 4; r += 2) {
                u32 pk = (u32)f2bf(y[rt][ct][r]) | ((u32)f2bf(y[rt][ct][r + 1]) << 16);
                *(u32*)&Y1[c2 * 132 + m0 + r] = pk;
            }
#pragma unroll
            for (int r = 0; r < 4; ++r) XY[(m0 + r) * 68 + c2] = f2bf(y[rt][ct][r]);
        }
    __syncthreads();

    // ---- GEMM2: acc2 = Wp @ Y1 ----
    f32x4 acc2[2][4];
#pragma unroll
    for (int rt = 0; rt < 2; ++rt)
#pragma unroll
        for (int ct = 0; ct < 4; ++ct)
#pragma unroll
            for (int r = 0; r < 4; ++r) acc2[rt][ct][r] = 0.f;

    const bf16_t* wp0 = Wp + (size_t)(w * 32 + lr) * 128 + g * 8;
#pragma unroll
    for (int ks = 0; ks < 4; ++ks) {
        bf16x8 af0 = *(const bf16x8*)(wp0 + ks * 32);
        bf16x8 af1 = *(const bf16x8*)(wp0 + 16 * 128 + ks * 32);
#pragma unroll
        for (int ct = 0; ct < 4; ++ct) {
            BF8 bu;
            const u16* p = &Y1[(ct * 16 + lr) * 132 + ks * 32 + g * 8];
            bu.u4[0] = *(const ushort4*)p;
            bu.u4[1] = *(const ushort4*)(p + 4);
            acc2[0][ct] = __builtin_amdgcn_mfma_f32_16x16x32_bf16(af0, bu.v, acc2[0][ct], 0, 0, 0);
            acc2[1][ct] = __builtin_amdgcn_mfma_f32_16x16x32_bf16(af1, bu.v, acc2[1][ct], 0, 0, 0);
        }
    }

    // ---- write tanh-feature tile to global (bf16, n-contiguous) from Y1N=XY ----
    {
        u16* fb = (u16*)feat_out + (size_t)b * 128 * S + n0;
#pragma unroll
        for (int it = 0; it < 8; ++it) {
            int m = w * 32 + it * 4 + g;
            int nc = lr * 4;
            ushort4 v = *(const ushort4*)&XY[m * 68 + nc];
            *(ushort4*)(fb + (size_t)m * S + nc) = v;
        }
    }

    if constexpr (IMG) {
        // logits[n] = sum_a Watt[a]*tanh(qatt[a] + P[a,n])
        float ps[4] = {0, 0, 0, 0};
#pragma unroll
        for (int rt = 0; rt < 2; ++rt)
#pragma unroll
            for (int r = 0; r < 4; ++r) {
                int a = w * 32 + rt * 16 + g * 4 + r;
                float qa = qf_l[a], wv = wa_l[a];
#pragma unroll
                for (int ct = 0; ct < 4; ++ct) ps[ct] += wv * fast_tanh(qa + acc2[rt][ct][r]);
            }
#pragma unroll
        for (int ct = 0; ct < 4; ++ct) {
            ps[ct] += __shfl_xor(ps[ct], 16, 64);
            ps[ct] += __shfl_xor(ps[ct], 32, 64);
        }
        if (g == 0) {
#pragma unroll
            for (int ct = 0; ct < 4; ++ct) lred[w][ct * 16 + lr] = ps[ct];
        }
        __syncthreads();
        if (tid < 64)
            proj_out[(size_t)b * NTOT + n0 + tid] =
                lred[0][tid] + lred[1][tid] + lred[2][tid] + lred[3][tid];
    } else {
        // store raw projection P[a,t] (f32)
#pragma unroll
        for (int rt = 0; rt < 2; ++rt)
#pragma unroll
            for (int ct = 0; ct < 4; ++ct) {
                int a = w * 32 + rt * 16 + g * 4;
                int t = n0 + ct * 16 + lr;
#pragma unroll
                for (int r = 0; r < 4; ++r)
                    proj_out[((size_t)b * 128 + a + r) * 128 + t] = acc2[rt][ct][r];
            }
    }
}

// ---------------- launch ----------------
extern "C" void kernel_launch(void* const* d_in, const int* in_sizes, int n_in, void* d_out,
                              int out_size, void* d_ws, size_t ws_size, hipStream_t stream) {
    (void)in_sizes; (void)n_in; (void)out_size; (void)ws_size;
    const float* img  = (const float*)d_in[0];
    const float* txt  = (const float*)d_in[1];
    const float* Wimg = (const float*)d_in[2];
    const float* Wtxt = (const float*)d_in[3];
    const float* Wqfc = (const float*)d_in[4];
    const float* Wifc = (const float*)d_in[5];
    const float* Wipc = (const float*)d_in[6];
    const float* Wqpc = (const float*)d_in[7];
    const float* Watt = (const float*)d_in[8];

    char* ws = (char*)d_ws;
    bf16_t* wimg_b  = (bf16_t*)(ws + WS_WIMG);
    bf16_t* wtxt_b  = (bf16_t*)(ws + WS_WTXT);
    bf16_t* wipc_b  = (bf16_t*)(ws + WS_WIPC);
    bf16_t* wqpc_b  = (bf16_t*)(ws + WS_WQPC);
    bf16_t* ifeat_b = (bf16_t*)(ws + WS_IFEAT);
    bf16_t* qfeat_b = (bf16_t*)(ws + WS_QFEAT);
    float*  qfp     = (float*)(ws + WS_QFP);
    float*  logits  = (float*)(ws + WS_LOGIT);
    float*  isum    = (float*)(ws + WS_ISUM);
    float*  qsum    = (float*)(ws + WS_QSUM);
    float*  qatt    = (float*)(ws + WS_QATT);

    float* out_feat = (float*)d_out;             // [64,128]
    float* out_att  = (float*)d_out + 64 * 128;  // [64,4224]

    // zero atomic accumulators (isum+qsum contiguous) and out_feat
    k_zero<<<(2 * 64 * 128 + 255) / 256, 256, 0, stream>>>(isum, 2 * 64 * 128);
    k_zero<<<(64 * 128 + 255) / 256, 256, 0, stream>>>(out_feat, 64 * 128);

    k_convert4<<<131072 / 256, 256, 0, stream>>>(Wimg, Wtxt, Wipc, Wqpc,
                                                 wimg_b, wtxt_b, wipc_b, wqpc_b);

    // text chain: in_qfeat (bf16), qsum, qfeatproj (f32)
    k_chain<512, false><<<dim3(2, 64), 256, 0, stream>>>(txt, wtxt_b, wqpc_b, nullptr, nullptr,
                                                         qfeat_b, qsum, qfp, TT);
    // qfeatatt
    k_qatt<<<64, 128, 0, stream>>>(qsum, Wqfc, qatt);
    // image chain: in_ifeat (bf16), isum, image logits
    k_chain<256, true><<<dim3(64, 64), 256, 0, stream>>>(img, wimg_b, wipc_b, qatt, Watt,
                                                         ifeat_b, isum, logits, HW);
    // text-branch logits
    k_textlogits<<<64, 256, 0, stream>>>(isum, Wifc, Watt, qfp, logits);
    // softmax -> att (directly into d_out att region)
    k_softmax<<<64, 256, 0, stream>>>(logits, out_att);
    // att_feat (atomic accumulate into zeroed out_feat)
    k_attfeat<<<dim3(16, 4, 64), 256, 0, stream>>>(ifeat_b, qfeat_b, out_att, out_feat);
}

// Round 5
// 485.328 us; speedup vs baseline: 1.0371x; 1.0134x over previous
//
#include <hip/hip_runtime.h>
#include <hip/hip_bf16.h>

#define DI static __device__ __forceinline__

typedef unsigned short u16;
typedef unsigned int   u32;
typedef __bf16 bf16_t;
typedef __bf16 bf16x8 __attribute__((ext_vector_type(8)));
typedef float  f32x4  __attribute__((ext_vector_type(4)));

union BF8 { ushort4 u4[2]; bf16x8 v; };

DI u16 f2bf(float f) { union { bf16_t b; u16 u; } c; c.b = (bf16_t)f; return c.u; }
DI float bf2f(u32 lo) { union { u32 u; float f; } c; c.u = lo << 16; return c.f; }
DI float fast_tanh(float x) { float e = __expf(2.0f * x); return 1.0f - 2.0f / (e + 1.0f); }

// ---------------- problem constants ----------------
constexpr int NB   = 64;
constexpr int HW   = 4096;
constexpr int TT   = 128;
constexpr int NTOT = HW + TT; // 4224

// ---------------- ws layout (bytes) ----------------
constexpr size_t WS_WIMG  = 0;                                  // 128*256 bf16
constexpr size_t WS_WTXT  = WS_WIMG  + 128ull*256*2;            // 128*512 bf16
constexpr size_t WS_WIPC  = WS_WTXT  + 128ull*512*2;            // 128*128 bf16
constexpr size_t WS_WQPC  = WS_WIPC  + 128ull*128*2;            // 128*128 bf16
constexpr size_t WS_IFEAT = WS_WQPC  + 128ull*128*2;            // 64*128*4096 bf16
constexpr size_t WS_QFEAT = WS_IFEAT + (size_t)NB*128*HW*2;     // 64*128*128 bf16
constexpr size_t WS_QFP   = WS_QFEAT + (size_t)NB*128*TT*2;     // 64*128*128 f32
constexpr size_t WS_LOGIT = WS_QFP   + (size_t)NB*128*TT*4;     // 64*4096 f32 (image logits)
constexpr size_t WS_ISUM  = WS_LOGIT + (size_t)NB*HW*4;         // 64*128 f32
constexpr size_t WS_QSUM  = WS_ISUM  + (size_t)NB*128*4;        // 64*128 f32

// ---------------- init: zero accumulators + convert all weights ----------------
__global__ void k_init(const float* __restrict__ s0, const float* __restrict__ s1,
                       const float* __restrict__ s2, const float* __restrict__ s3,
                       bf16_t* __restrict__ d0, bf16_t* __restrict__ d1,
                       bf16_t* __restrict__ d2, bf16_t* __restrict__ d3,
                       float* __restrict__ sums, float* __restrict__ outf) {
    int i = blockIdx.x * 256 + threadIdx.x;  // 131072 total
    if (i < 16384) sums[i] = 0.f;            // isum+qsum contiguous
    else if (i < 24576) outf[i - 16384] = 0.f;
    int j = i;
    if (j < 32768) { d0[j] = (bf16_t)s0[j]; return; }
    j -= 32768;
    if (j < 65536) { d1[j] = (bf16_t)s1[j]; return; }
    j -= 65536;
    if (j < 16384) { d2[j] = (bf16_t)s2[j]; return; }
    j -= 16384;
    d3[j] = (bf16_t)s3[j];
}

// ---------------- fused chain kernel ----------------
// Per 64-column tile of batch b:
//   Y1 = tanh(Wa @ X)  (GEMM1, double-buffered 64-row K-chunks w/ reg prefetch)
//   P  = Wp @ Y1       (GEMM2)
//   IMG:  qatt inline; logits[n] = sum_a Watt[a]*tanh(qatt[a]+P[a,n]) -> proj_out [b,4096]
//   !IMG: proj_out[b,a,t] = P[a,t] (f32)
// LDS 36.3 KB -> 4 blocks/CU.
template <int C, bool IMG>
__global__ __launch_bounds__(256, 4) void k_chain(
    const float* __restrict__ xin, const bf16_t* __restrict__ Wa, const bf16_t* __restrict__ Wp,
    const float* __restrict__ qsum, const float* __restrict__ Wqfc, const float* __restrict__ Watt,
    bf16_t* __restrict__ feat_out, float* __restrict__ sums, float* __restrict__ proj_out, int S) {
    constexpr int NCH = C / 64;        // 64-row K-chunks
    __shared__ u16 XY[2][64 * 68];     // chunk buffers [col][c2]; later Y1N flat [128][68]
    __shared__ u16 Y1[64 * 132];       // Y1[col][m] (GEMM2 B-frags)
    __shared__ float lred[4][64];
    __shared__ float qf_l[128];
    __shared__ float wa_l[128];

    const int tid = threadIdx.x;
    const int b  = blockIdx.y;
    const int n0 = blockIdx.x * 64;
    const int l  = tid & 63, w = tid >> 6;
    const int lr = l & 15, g = l >> 4;

    f32x4 acc1[2][4];
#pragma unroll
    for (int rt = 0; rt < 2; ++rt)
#pragma unroll
        for (int ct = 0; ct < 4; ++ct)
#pragma unroll
            for (int r = 0; r < 4; ++r) acc1[rt][ct][r] = 0.f;

    const bf16_t* wa0 = Wa + (size_t)(w * 32 + lr) * C + g * 8;
    const int colb = (tid & 15) * 4;   // 4 cols per thread
    const int rb   = tid >> 4;         // 0..15; rows rb + p*16
    const float* xbase = xin + (size_t)b * C * S + n0 + colb;
    float4 pf[4];

    // prologue: chunk 0
#pragma unroll
    for (int p = 0; p < 4; ++p) pf[p] = *(const float4*)(xbase + (size_t)(rb + p * 16) * S);
#pragma unroll
    for (int p = 0; p < 4; ++p) {
        int c2 = rb + p * 16;
        u16 v[4] = {f2bf(pf[p].x), f2bf(pf[p].y), f2bf(pf[p].z), f2bf(pf[p].w)};
        int rot = c2 & 3;
#pragma unroll
        for (int s = 0; s < 4; ++s) { int jj = (s + rot) & 3; XY[0][(colb + jj) * 68 + c2] = v[jj]; }
    }

    for (int h = 0; h < NCH; ++h) {
        __syncthreads();  // buffer h&1 ready for all; prev commits/MFMAs fenced
        if (h + 1 < NCH) {
            const float* xb = xbase + (size_t)((h + 1) * 64) * S;
#pragma unroll
            for (int p = 0; p < 4; ++p) pf[p] = *(const float4*)(xb + (size_t)(rb + p * 16) * S);
        }
        // MFMA on chunk h
#pragma unroll
        for (int ks2 = 0; ks2 < 2; ++ks2) {
            int ks = h * 2 + ks2;
            bf16x8 af0 = *(const bf16x8*)(wa0 + ks * 32);
            bf16x8 af1 = *(const bf16x8*)(wa0 + (size_t)16 * C + ks * 32);
#pragma unroll
            for (int ct = 0; ct < 4; ++ct) {
                BF8 bu;
                const u16* p = &XY[h & 1][(ct * 16 + lr) * 68 + ks2 * 32 + g * 8];
                bu.u4[0] = *(const ushort4*)p;
                bu.u4[1] = *(const ushort4*)(p + 4);
                acc1[0][ct] = __builtin_amdgcn_mfma_f32_16x16x32_bf16(af0, bu.v, acc1[0][ct], 0, 0, 0);
                acc1[1][ct] = __builtin_amdgcn_mfma_f32_16x16x32_bf16(af1, bu.v, acc1[1][ct], 0, 0, 0);
            }
        }
        if (h + 1 < NCH) {
#pragma unroll
            for (int p = 0; p < 4; ++p) {
                int c2 = rb + p * 16;
                u16 v[4] = {f2bf(pf[p].x), f2bf(pf[p].y), f2bf(pf[p].z), f2bf(pf[p].w)};
                int rot = c2 & 3;
#pragma unroll
                for (int s = 0; s < 4; ++s) {
                    int jj = (s + rot) & 3;
                    XY[(h + 1) & 1][(colb + jj) * 68 + c2] = v[jj];
                }
            }
        }
    }
    __syncthreads();  // all MFMA reads of XY done before Y1N overwrite

    // ---- tanh in place; row sums (for mean) ----
#pragma unroll
    for (int rt = 0; rt < 2; ++rt)
#pragma unroll
        for (int ct = 0; ct < 4; ++ct)
#pragma unroll
            for (int r = 0; r < 4; ++r) acc1[rt][ct][r] = fast_tanh(acc1[rt][ct][r]);

#pragma unroll
    for (int rt = 0; rt < 2; ++rt)
#pragma unroll
        for (int r = 0; r < 4; ++r) {
            float s = acc1[rt][0][r] + acc1[rt][1][r] + acc1[rt][2][r] + acc1[rt][3][r];
            s += __shfl_xor(s, 1, 64);
            s += __shfl_xor(s, 2, 64);
            s += __shfl_xor(s, 4, 64);
            s += __shfl_xor(s, 8, 64);
            if (lr == 0) atomicAdd(&sums[b * 128 + w * 32 + rt * 16 + g * 4 + r], s);
        }

    // ---- scatter Y1 (m-major) + Y1N (n-major, aliases XY flat [128][68]) ----
    u16* Y1N = &XY[0][0];
#pragma unroll
    for (int rt = 0; rt < 2; ++rt)
#pragma unroll
        for (int ct = 0; ct < 4; ++ct) {
            int m0 = w * 32 + rt * 16 + g * 4;
            int c2 = ct * 16 + lr;
#pragma unroll
            for (int r = 0; r < 4; r += 2) {
                u32 pk = (u32)f2bf(acc1[rt][ct][r]) | ((u32)f2bf(acc1[rt][ct][r + 1]) << 16);
                *(u32*)&Y1[c2 * 132 + m0 + r] = pk;
            }
#pragma unroll
            for (int r = 0; r < 4; ++r) Y1N[(m0 + r) * 68 + c2] = f2bf(acc1[rt][ct][r]);
        }
    __syncthreads();

    // ---- inline qatt (IMG): qf_l[a] = dot(qsum[b,:], Wqfc[a,:]) / 128 ----
    if constexpr (IMG) {
        if (tid < 128) {
            const float4* qs4 = (const float4*)(qsum + b * 128);
            const float4* wr4 = (const float4*)(Wqfc + (size_t)tid * 128);
            float s = 0.f;
#pragma unroll 8
            for (int m = 0; m < 32; ++m) {
                float4 a = qs4[m], c = wr4[m];
                s += a.x * c.x + a.y * c.y + a.z * c.z + a.w * c.w;
            }
            qf_l[tid] = s * (1.0f / 128.0f);
            wa_l[tid] = Watt[tid];
        }
    }

    // ---- GEMM2: acc2 = Wp @ Y1 ----
    f32x4 acc2[2][4];
#pragma unroll
    for (int rt = 0; rt < 2; ++rt)
#pragma unroll
        for (int ct = 0; ct < 4; ++ct)
#pragma unroll
            for (int r = 0; r < 4; ++r) acc2[rt][ct][r] = 0.f;

    const bf16_t* wp0 = Wp + (size_t)(w * 32 + lr) * 128 + g * 8;
#pragma unroll
    for (int ks = 0; ks < 4; ++ks) {
        bf16x8 af0 = *(const bf16x8*)(wp0 + ks * 32);
        bf16x8 af1 = *(const bf16x8*)(wp0 + 16 * 128 + ks * 32);
#pragma unroll
        for (int ct = 0; ct < 4; ++ct) {
            BF8 bu;
            const u16* p = &Y1[(ct * 16 + lr) * 132 + ks * 32 + g * 8];
            bu.u4[0] = *(const ushort4*)p;
            bu.u4[1] = *(const ushort4*)(p + 4);
            acc2[0][ct] = __builtin_amdgcn_mfma_f32_16x16x32_bf16(af0, bu.v, acc2[0][ct], 0, 0, 0);
            acc2[1][ct] = __builtin_amdgcn_mfma_f32_16x16x32_bf16(af1, bu.v, acc2[1][ct], 0, 0, 0);
        }
    }

    // ---- write tanh-feature tile to global (bf16, n-contiguous) from Y1N ----
    {
        u16* fb = (u16*)feat_out + (size_t)b * 128 * S + n0;
#pragma unroll
        for (int it = 0; it < 8; ++it) {
            int m = w * 32 + it * 4 + g;
            int nc = lr * 4;
            ushort4 v = *(const ushort4*)&Y1N[m * 68 + nc];
            *(ushort4*)(fb + (size_t)m * S + nc) = v;
        }
    }

    if constexpr (IMG) {
        __syncthreads();  // qf_l/wa_l ready
        // logits[n] = sum_a Watt[a]*tanh(qatt[a] + P[a,n])
        float ps[4] = {0, 0, 0, 0};
#pragma unroll
        for (int rt = 0; rt < 2; ++rt)
#pragma unroll
            for (int r = 0; r < 4; ++r) {
                int a = w * 32 + rt * 16 + g * 4 + r;
                float qa = qf_l[a], wv = wa_l[a];
#pragma unroll
                for (int ct = 0; ct < 4; ++ct) ps[ct] += wv * fast_tanh(qa + acc2[rt][ct][r]);
            }
#pragma unroll
        for (int ct = 0; ct < 4; ++ct) {
            ps[ct] += __shfl_xor(ps[ct], 16, 64);
            ps[ct] += __shfl_xor(ps[ct], 32, 64);
        }
        if (g == 0) {
#pragma unroll
            for (int ct = 0; ct < 4; ++ct) lred[w][ct * 16 + lr] = ps[ct];
        }
        __syncthreads();
        if (tid < 64)
            proj_out[(size_t)b * HW + n0 + tid] =
                lred[0][tid] + lred[1][tid] + lred[2][tid] + lred[3][tid];
    } else {
        // store raw projection P[a,t] (f32)
#pragma unroll
        for (int rt = 0; rt < 2; ++rt)
#pragma unroll
            for (int ct = 0; ct < 4; ++ct) {
                int a = w * 32 + rt * 16 + g * 4;
                int t = n0 + ct * 16 + lr;
#pragma unroll
                for (int r = 0; r < 4; ++r)
                    proj_out[((size_t)b * 128 + a + r) * 128 + t] = acc2[rt][ct][r];
            }
    }
}

// ---------------- finish: ifeatatt + text logits + softmax -> att ----------------
__global__ void k_finish(const float* __restrict__ isum, const float* __restrict__ Wifc,
                         const float* __restrict__ Watt, const float* __restrict__ qfp,
                         const float* __restrict__ logitsI, float* __restrict__ att) {
    int b = blockIdx.x, tid = threadIdx.x;  // 256 threads
    __shared__ float L[NTOT];
    __shared__ float ia[128];
    __shared__ float wat[128];
    __shared__ float part[2][128];
    __shared__ float redm[4];
    __shared__ float reds[4];

    if (tid < 128) {
        const float4* is4 = (const float4*)(isum + b * 128);
        const float4* wr4 = (const float4*)(Wifc + (size_t)tid * 128);
        float s = 0.f;
#pragma unroll 8
        for (int m = 0; m < 32; ++m) {
            float4 a = is4[m], c = wr4[m];
            s += a.x * c.x + a.y * c.y + a.z * c.z + a.w * c.w;
        }
        ia[tid]  = s * (1.0f / 4096.0f);
        wat[tid] = Watt[tid];
    }
    // image logits -> LDS
    const float4* LI = (const float4*)(logitsI + (size_t)b * HW);
#pragma unroll
    for (int i = 0; i < 4; ++i) *(float4*)&L[(i * 256 + tid) * 4] = LI[i * 256 + tid];
    __syncthreads();

    // text logits
    {
        int t = tid & 127, h = tid >> 7;
        const float* qp = qfp + ((size_t)b * 128 + h * 64) * 128 + t;
        float s = 0.f;
        for (int a0 = 0; a0 < 64; ++a0)
            s += wat[h * 64 + a0] * fast_tanh(ia[h * 64 + a0] + qp[(size_t)a0 * 128]);
        part[h][t] = s;
    }
    __syncthreads();
    if (tid < 128) L[HW + tid] = part[0][tid] + part[1][tid];
    __syncthreads();

    // softmax over L[0..4223]
    float* O = att + (size_t)b * NTOT;
    float mx = -3.0e38f;
    for (int i = tid; i < NTOT; i += 256) mx = fmaxf(mx, L[i]);
    for (int off = 1; off < 64; off <<= 1) mx = fmaxf(mx, __shfl_xor(mx, off, 64));
    if ((tid & 63) == 0) redm[tid >> 6] = mx;
    __syncthreads();
    mx = fmaxf(fmaxf(redm[0], redm[1]), fmaxf(redm[2], redm[3]));
    float s = 0.f;
    for (int i = tid; i < NTOT; i += 256) {
        float e = __expf(L[i] - mx);
        L[i] = e;
        s += e;
    }
    for (int off = 1; off < 64; off <<= 1) s += __shfl_xor(s, off, 64);
    if ((tid & 63) == 0) reds[tid >> 6] = s;
    __syncthreads();
    float inv = 1.0f / (reds[0] + reds[1] + reds[2] + reds[3]);
    for (int i = tid; i < NTOT; i += 256) O[i] = L[i] * inv;
}

// ---------------- att_feat: 16B loads, 4-way n-split, atomic accumulate ----------------
__global__ void k_attfeat(const bf16_t* __restrict__ ifeat, const bf16_t* __restrict__ qfeat,
                          const float* __restrict__ att, float* __restrict__ out) {
    int mg = blockIdx.x;   // 16 groups of 8 rows
    int ns = blockIdx.y;   // 4 n-splits of 1024
    int b  = blockIdx.z;
    int tid = threadIdx.x; // 256
    int half = tid >> 7;   // rows mg*8 + half*4 + r
    int q = tid & 127;
    int cx = q * 8;        // 8 cols per thread
    const float* A_ = att + (size_t)b * NTOT;
    const u16* F = (const u16*)ifeat + ((size_t)b * 128 + mg * 8 + half * 4) * HW + ns * 1024 + cx;

    float a8[8];
    {
        float4 a0 = *(const float4*)&A_[ns * 1024 + cx];
        float4 a1 = *(const float4*)&A_[ns * 1024 + cx + 4];
        a8[0] = a0.x; a8[1] = a0.y; a8[2] = a0.z; a8[3] = a0.w;
        a8[4] = a1.x; a8[5] = a1.y; a8[6] = a1.z; a8[7] = a1.w;
    }
    float acc[4] = {0, 0, 0, 0};
#pragma unroll
    for (int r = 0; r < 4; ++r) {
        uint4 pk = *(const uint4*)&F[(size_t)r * HW];
        acc[r] += bf2f(pk.x & 0xffffu) * a8[0] + bf2f(pk.x >> 16) * a8[1]
                + bf2f(pk.y & 0xffffu) * a8[2] + bf2f(pk.y >> 16) * a8[3]
                + bf2f(pk.z & 0xffffu) * a8[4] + bf2f(pk.z >> 16) * a8[5]
                + bf2f(pk.w & 0xffffu) * a8[6] + bf2f(pk.w >> 16) * a8[7];
    }
    if (ns == 0 && q < 16) {  // text part: 128 cols
        const u16* Q = (const u16*)qfeat + ((size_t)b * 128 + mg * 8 + half * 4) * TT + cx;
        float b8[8];
        float4 a0 = *(const float4*)&A_[HW + cx];
        float4 a1 = *(const float4*)&A_[HW + cx + 4];
        b8[0] = a0.x; b8[1] = a0.y; b8[2] = a0.z; b8[3] = a0.w;
        b8[4] = a1.x; b8[5] = a1.y; b8[6] = a1.z; b8[7] = a1.w;
#pragma unroll
        for (int r = 0; r < 4; ++r) {
            uint4 pk = *(const uint4*)&Q[(size_t)r * TT];
            acc[r] += bf2f(pk.x & 0xffffu) * b8[0] + bf2f(pk.x >> 16) * b8[1]
                    + bf2f(pk.y & 0xffffu) * b8[2] + bf2f(pk.y >> 16) * b8[3]
                    + bf2f(pk.z & 0xffffu) * b8[4] + bf2f(pk.z >> 16) * b8[5]
                    + bf2f(pk.w & 0xffffu) * b8[6] + bf2f(pk.w >> 16) * b8[7];
        }
    }
    __shared__ float red[4][4];
    int lane = tid & 63, wv = tid >> 6;
#pragma unroll
    for (int r = 0; r < 4; ++r) {
        float s = acc[r];
        s += __shfl_xor(s, 1, 64);
        s += __shfl_xor(s, 2, 64);
        s += __shfl_xor(s, 4, 64);
        s += __shfl_xor(s, 8, 64);
        s += __shfl_xor(s, 16, 64);
        s += __shfl_xor(s, 32, 64);
        if (lane == 0) red[wv][r] = s;
    }
    __syncthreads();
    if (tid < 8) {
        int rr = tid & 3, hh = tid >> 2;
        atomicAdd(&out[(size_t)b * 128 + mg * 8 + hh * 4 + rr],
                  red[2 * hh][rr] + red[2 * hh + 1][rr]);
    }
}

// ---------------- launch ----------------
extern "C" void kernel_launch(void* const* d_in, const int* in_sizes, int n_in, void* d_out,
                              int out_size, void* d_ws, size_t ws_size, hipStream_t stream) {
    (void)in_sizes; (void)n_in; (void)out_size; (void)ws_size;
    const float* img  = (const float*)d_in[0];
    const float* txt  = (const float*)d_in[1];
    const float* Wimg = (const float*)d_in[2];
    const float* Wtxt = (const float*)d_in[3];
    const float* Wqfc = (const float*)d_in[4];
    const float* Wifc = (const float*)d_in[5];
    const float* Wipc = (const float*)d_in[6];
    const float* Wqpc = (const float*)d_in[7];
    const float* Watt = (const float*)d_in[8];

    char* ws = (char*)d_ws;
    bf16_t* wimg_b  = (bf16_t*)(ws + WS_WIMG);
    bf16_t* wtxt_b  = (bf16_t*)(ws + WS_WTXT);
    bf16_t* wipc_b  = (bf16_t*)(ws + WS_WIPC);
    bf16_t* wqpc_b  = (bf16_t*)(ws + WS_WQPC);
    bf16_t* ifeat_b = (bf16_t*)(ws + WS_IFEAT);
    bf16_t* qfeat_b = (bf16_t*)(ws + WS_QFEAT);
    float*  qfp     = (float*)(ws + WS_QFP);
    float*  logits  = (float*)(ws + WS_LOGIT);
    float*  isum    = (float*)(ws + WS_ISUM);
    float*  qsum    = (float*)(ws + WS_QSUM);

    float* out_feat = (float*)d_out;             // [64,128]
    float* out_att  = (float*)d_out + 64 * 128;  // [64,4224]

    // init: zero isum/qsum/out_feat + convert weights (1 launch)
    k_init<<<131072 / 256, 256, 0, stream>>>(Wimg, Wtxt, Wipc, Wqpc, wimg_b, wtxt_b, wipc_b,
                                             wqpc_b, isum, out_feat);
    // text chain: in_qfeat (bf16), qsum, qfeatproj (f32)
    k_chain<512, false><<<dim3(2, 64), 256, 0, stream>>>(txt, wtxt_b, wqpc_b, nullptr, nullptr,
                                                         nullptr, qfeat_b, qsum, qfp, TT);
    // image chain (qatt inline): in_ifeat (bf16), isum, image logits
    k_chain<256, true><<<dim3(64, 64), 256, 0, stream>>>(img, wimg_b, wipc_b, qsum, Wqfc, Watt,
                                                         ifeat_b, isum, logits, HW);
    // ifeatatt + text logits + softmax -> att
    k_finish<<<64, 256, 0, stream>>>(isum, Wifc, Watt, qfp, logits, out_att);
    // att_feat (atomic accumulate into zeroed out_feat)
    k_attfeat<<<dim3(16, 4, 64), 256, 0, stream>>>(ifeat_b, qfeat_b, out_att, out_feat);
}